// Round 1
// baseline (124.449 us; speedup 1.0000x reference)
//
#include <hip/hip_runtime.h>

// Problem constants
#define NSEG   4480     // 70 * 64
#define ADIM   64
#define BDIM   16
#define NEDGE  65536
#define UPITCH 1088     // bf16 elements per U row: 1024 kernel-cols + 64 bias-cols (2176 B)
#define KP     72       // LDS pitch (bf16 elems) for 64-deep K tiles: 64 + 8 pad

// Workspace layout (ws is 256 MiB, poisoned each iteration by harness):
//   U    @ 0        : 4480*1088*2 = 9,748,480 B  (bf16 projections)
//   msg  @ 16 MiB   : 65536*64*4  = 16,777,216 B (f32 per-edge messages)
//   ints @ 40 MiB   : CSR arrays (see kernel_launch)
#define MSG_OFF  (16u << 20)
#define INT_OFF  (40u << 20)

typedef __bf16 bf16x8 __attribute__((ext_vector_type(8)));
typedef float  f32x4  __attribute__((ext_vector_type(4)));

__device__ __forceinline__ float bf2f(unsigned int bits_hi16) {
    union { unsigned int i; float f; } c; c.i = bits_hi16; return c.f;
}
__device__ __forceinline__ unsigned short f2bf(float f) {
    union { float f; unsigned int i; } c; c.f = f;
    unsigned int x = c.i;
    x += 0x7fffu + ((x >> 16) & 1u);   // round-to-nearest-even
    return (unsigned short)(x >> 16);
}

// ---------------------------------------------------------------------------
// proj_kernel (MFMA): U[a, c] = sum_j atom[a,j] * W[j,c], stored bf16.
//   W[j,c] = kern[c&15, (c>>4)*64 + j]  (c < 1024;  c = i*16+b)
//   W[j,1024+i] = bias[i*64+j]          (bias cols)
// by==0 slice zeroes the CSR counter arrays (4*4480 ints = 70*256 exactly)
// instead of out[] — reduce_kernel now writes every out row directly.
// ---------------------------------------------------------------------------
__global__ __launch_bounds__(256) void proj_kernel(
    const float* __restrict__ atom,
    const float* __restrict__ kern,
    const float* __restrict__ bias,
    unsigned short* __restrict__ U,
    int* __restrict__ csr_ints)
{
    __shared__ unsigned short Al[64 * KP];   // A_bf16[row][k]
    __shared__ unsigned short Wl[64 * KP];   // W_bf16[c][k]  (n-major, k-contig)

    const int t      = threadIdx.x;
    const int bx     = blockIdx.x;      // 0..69  atom-row tile
    const int by     = blockIdx.y;      // 0..16  col tile (16 = bias)
    const int a_base = bx * 64;
    const int c_base = by * 64;

    if (by == 0) {
        // zero cnt_d, cnt_s, start_d, start_s: 4*4480 = 17920 ints = 70*256
        csr_ints[bx * 256 + t] = 0;
    }

    // ---- stage A tile: thread t -> row t>>2, k-quarter (t&3)*16 ----
    {
        const int row = t >> 2, q = t & 3;
        const float4* src = (const float4*)(atom + (size_t)(a_base + row) * ADIM + q * 16);
        unsigned short* dst = Al + row * KP + q * 16;
#pragma unroll
        for (int i = 0; i < 4; ++i) {
            float4 v = src[i];
            dst[i * 4 + 0] = f2bf(v.x);
            dst[i * 4 + 1] = f2bf(v.y);
            dst[i * 4 + 2] = f2bf(v.z);
            dst[i * 4 + 3] = f2bf(v.w);
        }
    }
    // ---- stage W tile: row c has its 64 k-values contiguous in kern/bias ----
    {
        const int crow = t >> 2, q = t & 3;
        const int c = c_base + crow;
        const float* bsrc = (c < 1024)
            ? (kern + (size_t)(c & 15) * 4096 + (size_t)(c >> 4) * 64)
            : (bias + (size_t)(c - 1024) * 64);
        const float4* src = (const float4*)(bsrc + q * 16);
        unsigned short* dst = Wl + crow * KP + q * 16;
#pragma unroll
        for (int i = 0; i < 4; ++i) {
            float4 v = src[i];
            dst[i * 4 + 0] = f2bf(v.x);
            dst[i * 4 + 1] = f2bf(v.y);
            dst[i * 4 + 2] = f2bf(v.z);
            dst[i * 4 + 3] = f2bf(v.w);
        }
    }
    __syncthreads();

    const int lane = t & 63;
    const int w    = t >> 6;        // wave id -> row sub-tile [w*16, w*16+16)
    const int m    = lane & 15;     // A row / B col / D col within tile
    const int quad = lane >> 4;

    f32x4 acc[4] = {{0.f,0.f,0.f,0.f},{0.f,0.f,0.f,0.f},
                    {0.f,0.f,0.f,0.f},{0.f,0.f,0.f,0.f}};

#pragma unroll
    for (int kk = 0; kk < 2; ++kk) {
        bf16x8 a = *(const bf16x8*)(Al + (w * 16 + m) * KP + kk * 32 + quad * 8);
#pragma unroll
        for (int ct = 0; ct < 4; ++ct) {
            bf16x8 b = *(const bf16x8*)(Wl + (ct * 16 + m) * KP + kk * 32 + quad * 8);
            acc[ct] = __builtin_amdgcn_mfma_f32_16x16x32_bf16(a, b, acc[ct], 0, 0, 0);
        }
    }

#pragma unroll
    for (int ct = 0; ct < 4; ++ct) {
#pragma unroll
        for (int r = 0; r < 4; ++r) {
            U[(size_t)(a_base + w * 16 + quad * 4 + r) * UPITCH
              + (c_base + ct * 16 + m)] = f2bf(acc[ct][r]);
        }
    }
}

// ---------------------------------------------------------------------------
// CSR build: hist -> scan -> scatter. Counters zeroed by proj_kernel (by==0).
// After scatter_kernel, start_x[s] has been advanced by cnt[s], i.e. it holds
// the group END; group begin for s is start_x[s-1] (post-scatter) or 0.
// ---------------------------------------------------------------------------
__global__ __launch_bounds__(256) void hist_kernel(
    const int* __restrict__ pair, int* __restrict__ cnt_d, int* __restrict__ cnt_s)
{
    const int e = blockIdx.x * 256 + threadIdx.x;
    const int2 p = ((const int2*)pair)[e];
    atomicAdd(&cnt_d[p.x], 1);
    atomicAdd(&cnt_s[p.y], 1);
}

// One wave, exclusive scan of 4480 = 64 lanes * 70 ints. No __syncthreads needed.
__device__ __forceinline__ void wave_scan_4480(
    const int* __restrict__ cnt, int* __restrict__ start)
{
    const int lane = threadIdx.x;      // 0..63
    const int base = lane * 70;
    int c[70];
    int run = 0;
#pragma unroll
    for (int i = 0; i < 70; ++i) { c[i] = cnt[base + i]; run += c[i]; }
    int incl = run;
#pragma unroll
    for (int d = 1; d < 64; d <<= 1) {
        int t = __shfl_up(incl, d, 64);
        if (lane >= d) incl += t;
    }
    int excl = incl - run;
#pragma unroll
    for (int i = 0; i < 70; ++i) { start[base + i] = excl; excl += c[i]; }
}

__global__ __launch_bounds__(64) void scan_kernel(
    const int* __restrict__ cnt_d, int* __restrict__ start_d,
    const int* __restrict__ cnt_s, int* __restrict__ start_s)
{
    wave_scan_4480(cnt_d, start_d);
    wave_scan_4480(cnt_s, start_s);
}

__global__ __launch_bounds__(256) void scatter_kernel(
    const int* __restrict__ pair,
    int* __restrict__ start_d, int* __restrict__ start_s,
    int* __restrict__ eidx_d, int* __restrict__ eidx_s)
{
    const int e = blockIdx.x * 256 + threadIdx.x;
    const int2 p = ((const int2*)pair)[e];
    eidx_d[atomicAdd(&start_d[p.x], 1)] = e;
    eidx_s[atomicAdd(&start_s[p.y], 1)] = e;
}

// ---------------------------------------------------------------------------
// msg_kernel: one wave per edge, processed in SRC-SORTED order (eidx_s) with
// XCD-chunked block swizzle: same-src edges (avg 14.6) run on the same
// CU/XCD, so the 2176 B U row is read once from L2/L3 and then hit in
// L1/L2 instead of re-streamed from L3 143 MB deep. Plain f32 store of the
// message — the 16.7M device-scope atomicAdds (cross-XCD serialized RMW,
// the suspected ~25 us) are gone.
// ---------------------------------------------------------------------------
__global__ __launch_bounds__(256) void msg_kernel(
    const float*          __restrict__ bond,
    const int*            __restrict__ pair,
    const int*            __restrict__ eidx_s,
    const unsigned short* __restrict__ U,
    float*                __restrict__ msg)
{
    const int t    = threadIdx.x;
    const int lane = t & 63;
    // 16384 blocks, 8 XCDs -> 2048 contiguous blocks per XCD (bijective)
    const int bx   = blockIdx.x;
    const int bsw  = (bx & 7) * 2048 + (bx >> 3);
    const int j    = bsw * 4 + (t >> 6);          // src-sorted position

    const int e   = eidx_s[j];                    // wave-uniform scalar load
    const int src = ((const int2*)pair)[e].y;

    const unsigned short* urow = U + (size_t)src * UPITCH;
    const uint4* up = (const uint4*)(urow + lane * 16);
    uint4 w0 = up[0];
    uint4 w1 = up[1];

    const float4* bp = (const float4*)(bond + (size_t)e * BDIM);
    float4 b0 = bp[0], b1 = bp[1], b2 = bp[2], b3 = bp[3];
    float b[16] = { b0.x, b0.y, b0.z, b0.w,  b1.x, b1.y, b1.z, b1.w,
                    b2.x, b2.y, b2.z, b2.w,  b3.x, b3.y, b3.z, b3.w };

    unsigned int w[8] = { w0.x, w0.y, w0.z, w0.w, w1.x, w1.y, w1.z, w1.w };

    float m = bf2f(((unsigned int)urow[1024 + lane]) << 16);   // bias col
#pragma unroll
    for (int q = 0; q < 8; ++q) {
        float lo = bf2f(w[q] << 16);           // element b = 2q
        float hi = bf2f(w[q] & 0xffff0000u);   // element b = 2q+1
        m = fmaf(lo, b[2 * q],     m);
        m = fmaf(hi, b[2 * q + 1], m);
    }

    msg[(size_t)e * ADIM + lane] = m;          // 256 B/wave, aligned, no RMW
}

// ---------------------------------------------------------------------------
// reduce_kernel: one wave per dst row; exclusive ownership -> plain store.
// begin/end from post-scatter start_d (see CSR comment). 4-wide chunk loop
// keeps ~4 independent msg loads in flight per wave.
// ---------------------------------------------------------------------------
__global__ __launch_bounds__(256) void reduce_kernel(
    const int*   __restrict__ start_d,
    const int*   __restrict__ eidx_d,
    const float* __restrict__ msg,
    float*       __restrict__ out)
{
    const int t    = threadIdx.x;
    const int lane = t & 63;
    const int d    = blockIdx.x * 4 + (t >> 6);   // 1120 blocks * 4 waves = 4480

    const int end   = start_d[d];
    const int begin = (d == 0) ? 0 : start_d[d - 1];

    float a0 = 0.f, a1 = 0.f, a2 = 0.f, a3 = 0.f;
    int k = begin;
    for (; k + 4 <= end; k += 4) {
        const int e0 = eidx_d[k + 0];
        const int e1 = eidx_d[k + 1];
        const int e2 = eidx_d[k + 2];
        const int e3 = eidx_d[k + 3];
        a0 += msg[(size_t)e0 * ADIM + lane];
        a1 += msg[(size_t)e1 * ADIM + lane];
        a2 += msg[(size_t)e2 * ADIM + lane];
        a3 += msg[(size_t)e3 * ADIM + lane];
    }
    for (; k < end; ++k) {
        a0 += msg[(size_t)eidx_d[k] * ADIM + lane];
    }

    out[(size_t)d * ADIM + lane] = (a0 + a1) + (a2 + a3);
}

extern "C" void kernel_launch(void* const* d_in, const int* in_sizes, int n_in,
                              void* d_out, int out_size, void* d_ws, size_t ws_size,
                              hipStream_t stream) {
    const float* atom = (const float*)d_in[0];   // [4480, 64]  f32
    const float* bond = (const float*)d_in[1];   // [65536, 16] f32
    const int*   pair = (const int*)  d_in[2];   // [65536, 2]  int32
    const float* kern = (const float*)d_in[3];   // [16, 4096]  f32
    const float* bias = (const float*)d_in[4];   // [4096]      f32

    float* out = (float*)d_out;                  // [4480, 64]  f32

    unsigned short* U  = (unsigned short*)d_ws;               // 9.75 MB bf16
    float* msg         = (float*)((char*)d_ws + MSG_OFF);     // 16.7 MB f32
    int*   ints        = (int*)  ((char*)d_ws + INT_OFF);
    int* cnt_d   = ints;                 // [4480]
    int* cnt_s   = ints + 4480;          // [4480]
    int* start_d = ints + 8960;          // [4480]
    int* start_s = ints + 13440;         // [4480]
    int* eidx_d  = ints + 17920;         // [65536]
    int* eidx_s  = ints + 17920 + NEDGE; // [65536]

    dim3 g1(NSEG / 64, UPITCH / 64);     // 70 x 17; by==0 zeroes CSR counters
    proj_kernel<<<g1, 256, 0, stream>>>(atom, kern, bias, U, ints);
    hist_kernel<<<NEDGE / 256, 256, 0, stream>>>(pair, cnt_d, cnt_s);
    scan_kernel<<<1, 64, 0, stream>>>(cnt_d, start_d, cnt_s, start_s);
    scatter_kernel<<<NEDGE / 256, 256, 0, stream>>>(pair, start_d, start_s,
                                                    eidx_d, eidx_s);
    msg_kernel<<<NEDGE / 4, 256, 0, stream>>>(bond, pair, eidx_s, U, msg);
    reduce_kernel<<<NSEG / 4, 256, 0, stream>>>(start_d, eidx_d, msg, out);
}

// Round 2
// 104.426 us; speedup vs baseline: 1.1917x; 1.1917x over previous
//
#include <hip/hip_runtime.h>

// Problem constants
#define NSEG   4480     // 70 * 64
#define ADIM   64
#define BDIM   16
#define NEDGE  65536
#define GP     1088     // G row pitch (bf16 elems): 17 slices * 64  (b-major, +bias slice)
#define CAP    128      // bucket capacity per dst (Poisson mean 14.6; P(>=128) ~ e^-167)
#define KP     72       // LDS pitch (bf16 elems): 64 + 8 pad -> 144 B rows, 2-way banks (free)

// Workspace layout (256 MiB, poisoned each iteration by the harness):
//   G   @ 0       : 4480*1088*2 = 9,748,480 B   (bf16 per-dst outer-product accumulators)
//   eb  @ 16 MiB  : 4480*128*8  = 4,587,520 B   (int2{edge, src} buckets)
//   cnt @ 24 MiB  : 4480*4      = 17,920 B      (bucket counters, memset to 0)
#define EB_OFF   (16u << 20)
#define CNT_OFF  (24u << 20)

typedef __bf16 bf16x8 __attribute__((ext_vector_type(8)));
typedef float  f32x4  __attribute__((ext_vector_type(4)));

__device__ __forceinline__ unsigned short f2bf(float f) {
    union { float f; unsigned int i; } c; c.f = f;
    unsigned int x = c.i;
    x += 0x7fffu + ((x >> 16) & 1u);   // round-to-nearest-even
    return (unsigned short)(x >> 16);
}

// ---------------------------------------------------------------------------
// scatter_kernel: append each edge to its destination's bucket.
// 65536 threads, one atomicAdd each on a 17.9 KB counter array (avg 14.6
// hits/counter) + one 8 B bucket store. Stores {e, src} so accum_kernel's
// bond and atom loads are independent (no pair re-read on the dep chain).
// ---------------------------------------------------------------------------
__global__ __launch_bounds__(256) void scatter_kernel(
    const int* __restrict__ pair, int* __restrict__ cnt, int2* __restrict__ eb)
{
    const int e  = blockIdx.x * 256 + threadIdx.x;
    const int2 p = ((const int2*)pair)[e];          // .x = dst, .y = src
    const int idx = atomicAdd(&cnt[p.x], 1);
    if (idx < CAP) eb[(size_t)p.x * CAP + idx] = make_int2(e, p.y);
}

// ---------------------------------------------------------------------------
// accum_kernel: one wave per dst. Builds
//   G[d, b*64+j] = sum_{e in dst(d)} bond[e,b] * atom[src_e, j]   (b < 16)
//   G[d, 16*64+j] = sum_{e in dst(d)} atom[src_e, j]              (bias slice)
// Lane j holds g[r] = G[d, r*64+j], r = 0..16 (17 f32 registers). Per edge:
// one coalesced 256 B atom-row load (atom = 1.1 MB, L2-resident on every
// XCD), one 64 B broadcast bond load, 17 wave-wide FMAs. Unroll-2 for MLP.
// No atomics anywhere; exact f32 accumulation, single bf16 rounding on store.
// ---------------------------------------------------------------------------
__global__ __launch_bounds__(256) void accum_kernel(
    const float* __restrict__ atom,
    const float* __restrict__ bond,
    const int*   __restrict__ cnt,
    const int2*  __restrict__ eb,
    unsigned short* __restrict__ G)
{
    const int t    = threadIdx.x;
    const int lane = t & 63;
    const int d    = blockIdx.x * 4 + (t >> 6);     // 1120 blocks * 4 waves = 4480
    const int nc   = cnt[d];
    const int n    = nc < CAP ? nc : CAP;
    const int2* bk = eb + (size_t)d * CAP;

    float g[17];
#pragma unroll
    for (int r = 0; r < 17; ++r) g[r] = 0.f;

    int k = 0;
    for (; k + 2 <= n; k += 2) {
        const int2 es0 = bk[k];
        const int2 es1 = bk[k + 1];
        const float a0 = atom[(size_t)es0.y * ADIM + lane];
        const float a1 = atom[(size_t)es1.y * ADIM + lane];
        const float4* b0p = (const float4*)(bond + (size_t)es0.x * BDIM);
        const float4* b1p = (const float4*)(bond + (size_t)es1.x * BDIM);
        float4 c0 = b0p[0], c1 = b0p[1], c2 = b0p[2], c3 = b0p[3];
        float4 e0 = b1p[0], e1 = b1p[1], e2 = b1p[2], e3 = b1p[3];
        const float bb0[16] = { c0.x,c0.y,c0.z,c0.w, c1.x,c1.y,c1.z,c1.w,
                                c2.x,c2.y,c2.z,c2.w, c3.x,c3.y,c3.z,c3.w };
        const float bb1[16] = { e0.x,e0.y,e0.z,e0.w, e1.x,e1.y,e1.z,e1.w,
                                e2.x,e2.y,e2.z,e2.w, e3.x,e3.y,e3.z,e3.w };
#pragma unroll
        for (int r = 0; r < 16; ++r) g[r] = fmaf(a0, bb0[r], g[r]);
        g[16] += a0;
#pragma unroll
        for (int r = 0; r < 16; ++r) g[r] = fmaf(a1, bb1[r], g[r]);
        g[16] += a1;
    }
    if (k < n) {
        const int2 es = bk[k];
        const float a = atom[(size_t)es.y * ADIM + lane];
        const float4* bp = (const float4*)(bond + (size_t)es.x * BDIM);
        float4 c0 = bp[0], c1 = bp[1], c2 = bp[2], c3 = bp[3];
        const float bb[16] = { c0.x,c0.y,c0.z,c0.w, c1.x,c1.y,c1.z,c1.w,
                               c2.x,c2.y,c2.z,c2.w, c3.x,c3.y,c3.z,c3.w };
#pragma unroll
        for (int r = 0; r < 16; ++r) g[r] = fmaf(a, bb[r], g[r]);
        g[16] += a;
    }

    // lane j writes G[d, r*64+j]: 128 B contiguous per r-step, coalesced
#pragma unroll
    for (int r = 0; r < 17; ++r)
        G[(size_t)d * GP + r * 64 + lane] = f2bf(g[r]);
}

// ---------------------------------------------------------------------------
// gemm_kernel: out[4480,64] = Ghat[4480,1088] @ K2[1088,64]   (bf16 MFMA)
//   K2[r*64+j, i] = kern[r, i*64+j]  (r < 16)   — kern row r IS the 64x64
//                   slice linearized [i*64+j], so staging is plain coalesced
//   K2[16*64+j,i] = bias[i*64+j]
// 280 blocks x 16 rows; 4 waves = 4 col-tiles of 16. K loop = 17 slices of
// 64, register-prefetched one slice ahead (global->reg->LDS). 2 MFMA per
// wave per slice. Every out row written -> no pre-zero, no atomics.
// Fragment layouts (m89/m91-verified): A/B: m|n=lane&15, k=quad*8+kk*32;
// C/D: col=lane&15, row=quad*4+reg.
// ---------------------------------------------------------------------------
__global__ __launch_bounds__(256) void gemm_kernel(
    const unsigned short* __restrict__ G,
    const float* __restrict__ kern,
    const float* __restrict__ bias,
    float* __restrict__ out)
{
    __shared__ unsigned short Gs[16 * KP];   // A tile: 16 rows x 64 k
    __shared__ unsigned short Ws[64 * KP];   // B tile: 64 cols x 64 k (n-major)

    const int t    = threadIdx.x;
    const int lane = t & 63;
    const int w    = t >> 6;                 // col tile ct = w
    const int rb   = blockIdx.x * 16;        // 280 blocks
    const int m    = lane & 15;
    const int quad = lane >> 4;

    const int wi = t >> 2, wq = t & 3;       // W staging: col i, k-quarter
    const int gr = t >> 3, gq = t & 7;       // G staging (t<128): row, k-eighth

    f32x4 acc = {0.f, 0.f, 0.f, 0.f};

    float4 wv[4];
    uint4  gv;
    {   // prefetch slice 0
        const float4* wp = (const float4*)(kern + (size_t)wi * 64 + wq * 16);
#pragma unroll
        for (int x = 0; x < 4; ++x) wv[x] = wp[x];
        if (t < 128)
            gv = *(const uint4*)(G + (size_t)(rb + gr) * GP + gq * 8);
    }

    for (int r = 0; r < 17; ++r) {
        __syncthreads();                     // frag reads of slice r-1 complete
        {   // regs -> LDS
            unsigned short* dst = Ws + wi * KP + wq * 16;
#pragma unroll
            for (int x = 0; x < 4; ++x) {
                float4 v = wv[x];
                dst[x * 4 + 0] = f2bf(v.x);
                dst[x * 4 + 1] = f2bf(v.y);
                dst[x * 4 + 2] = f2bf(v.z);
                dst[x * 4 + 3] = f2bf(v.w);
            }
            if (t < 128) *(uint4*)(Gs + gr * KP + gq * 8) = gv;
        }
        if (r + 1 < 17) {                    // issue next slice's globals now
            const float* wsrc = (r + 1 < 16) ? (kern + (size_t)(r + 1) * 4096)
                                             : bias;
            const float4* wp = (const float4*)(wsrc + (size_t)wi * 64 + wq * 16);
#pragma unroll
            for (int x = 0; x < 4; ++x) wv[x] = wp[x];
            if (t < 128)
                gv = *(const uint4*)(G + (size_t)(rb + gr) * GP
                                       + (r + 1) * 64 + gq * 8);
        }
        __syncthreads();
#pragma unroll
        for (int kk = 0; kk < 2; ++kk) {
            bf16x8 a = *(const bf16x8*)(Gs + m * KP + kk * 32 + quad * 8);
            bf16x8 b = *(const bf16x8*)(Ws + (w * 16 + m) * KP + kk * 32 + quad * 8);
            acc = __builtin_amdgcn_mfma_f32_16x16x32_bf16(a, b, acc, 0, 0, 0);
        }
    }

    // D: row = rb + quad*4 + rr, col = w*16 + m (quad's 16 lanes -> 64 B runs)
#pragma unroll
    for (int rr = 0; rr < 4; ++rr)
        out[(size_t)(rb + quad * 4 + rr) * ADIM + w * 16 + m] = acc[rr];
}

extern "C" void kernel_launch(void* const* d_in, const int* in_sizes, int n_in,
                              void* d_out, int out_size, void* d_ws, size_t ws_size,
                              hipStream_t stream) {
    const float* atom = (const float*)d_in[0];   // [4480, 64]  f32
    const float* bond = (const float*)d_in[1];   // [65536, 16] f32
    const int*   pair = (const int*)  d_in[2];   // [65536, 2]  int32
    const float* kern = (const float*)d_in[3];   // [16, 4096]  f32
    const float* bias = (const float*)d_in[4];   // [4096]      f32

    float* out = (float*)d_out;                  // [4480, 64]  f32

    unsigned short* G = (unsigned short*)d_ws;               // 9.75 MB bf16
    int2* eb = (int2*)((char*)d_ws + EB_OFF);                // 4.6 MB buckets
    int*  cnt = (int*)((char*)d_ws + CNT_OFF);               // 17.9 KB counters

    hipMemsetAsync(cnt, 0, NSEG * sizeof(int), stream);
    scatter_kernel<<<NEDGE / 256, 256, 0, stream>>>(pair, cnt, eb);
    accum_kernel<<<NSEG / 4, 256, 0, stream>>>(atom, bond, cnt, eb, G);
    gemm_kernel<<<NSEG / 16, 256, 0, stream>>>(G, kern, bias, out);
}